// Round 5
// baseline (119.642 us; speedup 1.0000x reference)
//
#include <hip/hip_runtime.h>
#include <hip/hip_bf16.h>

// Problem constants
#define B_    256
#define CIN   64
#define COUT  64
#define H_    1855
#define K_    6
#define KDIM  448          // (1 center + 6 neighbors) * 64 channels
#define NSTEP 14           // 448 / 32 (K per MFMA)
#define HT    64           // h-tile for transpose kernel
#define NHT   29           // ceil(1855/64)

// conv_main tiling
#define HT2   32           // h rows per conv tile
#define TPB   58           // tiles per b = ceil(1855/32)
#define NTILE (TPB * B_)   // 14848
#define TPBLK 8            // tiles per block
#define NBLK  (NTILE / TPBLK)   // 1856, % 8 == 0
#define CPX2  (NBLK / 8)        // 232

typedef __bf16 bf16x8 __attribute__((ext_vector_type(8)));
typedef float  f32x4  __attribute__((ext_vector_type(4)));

typedef __attribute__((address_space(3))) unsigned int       lds_u32;
typedef const __attribute__((address_space(1))) unsigned int glb_u32;

static __device__ inline unsigned short f2bf(float f) {
    __hip_bfloat16 h = __float2bfloat16(f);
    return *reinterpret_cast<unsigned short*>(&h);
}

// ---------------------------------------------------------------------------
// Kernel 1: pack weights into MFMA A-fragment order (bf16) + 1/total_valid
// Also zeroes the 128-B zbuf.
// ---------------------------------------------------------------------------
__global__ void prep_weights(const float* __restrict__ wc,
                             const float* __restrict__ wn,
                             const int*   __restrict__ nb,
                             unsigned short* __restrict__ W2,
                             float* __restrict__ inv_tv,
                             unsigned short* __restrict__ zbuf) {
    int e = blockIdx.x * 256 + threadIdx.x;     // 0 .. 28671
    int j = e & 7;
    int l = (e >> 3) & 63;
    int t = (e >> 9) & 3;
    int s = e >> 11;
    int o = t * 16 + (l & 15);
    int k = s * 32 + (l >> 4) * 8 + j;
    int slot = k >> 6;
    int c = k & 63;
    float v = (slot == 0) ? wc[o * 64 + c]
                          : wn[(o * 64 + c) * 6 + (slot - 1)];
    W2[e] = f2bf(v);
    if (blockIdx.x == 0 && threadIdx.x < 64) zbuf[threadIdx.x] = 0;
    if (e == 0) {
        int cnt = 1;
        #pragma unroll
        for (int q = 0; q < 6; ++q) cnt += (nb[q] >= 0) ? 1 : 0;
        *inv_tv = 1.0f / (float)cnt;
    }
}

// ---------------------------------------------------------------------------
// Kernel 2: transpose + convert  x (B, C, H) fp32  ->  xT (B, H, C) bf16
// ---------------------------------------------------------------------------
__global__ void transpose_bf16(const float* __restrict__ x,
                               unsigned short* __restrict__ xT) {
    __shared__ __align__(16) unsigned short tile[64][72];  // +8 pad
    int b  = blockIdx.y;
    int h0 = blockIdx.x * HT;
    int t  = threadIdx.x;
    int ho = t & 63;
    int cq = t >> 6;                       // 0..3
    const float* xb = x + (size_t)b * CIN * H_;
    int h = h0 + ho;
    #pragma unroll
    for (int i = 0; i < 16; ++i) {
        int c = i * 4 + cq;
        float v = (h < H_) ? xb[(size_t)c * H_ + h] : 0.f;
        tile[ho][c] = f2bf(v);
    }
    __syncthreads();
    #pragma unroll
    for (int rep = 0; rep < 2; ++rep) {
        int task = rep * 256 + t;          // 0..511  = 64 rows * 8 chunks
        int hh = task >> 3;
        int j  = task & 7;
        int hw = h0 + hh;
        if (hw < H_) {
            *reinterpret_cast<uint4*>(&xT[((size_t)b * H_ + hw) * 64 + j * 8]) =
                *reinterpret_cast<const uint4*>(&tile[hh][j * 8]);
        }
    }
}

// ---------------------------------------------------------------------------
// Kernel 3: persistent 8-tile pipeline, 256 threads = 4 waves.
// Compute: wave = og-pair (w&1) x h-subtile (w>>1); each wave reads one
// B-fragment from LDS and feeds TWO MFMAs (halves LDS read traffic vs the
// 8-wave 4-og layout). Weights for both o-tiles live in VGPRs (wr[14][2]).
// Staging: wave w gathers slots {w, w+4} (wave 3: slot 3 only) of the NEXT
// tile via global_load_lds (16B, source-side XOR swizzle); counted vmcnt
// keeps it in flight across barriers, hidden under compute of tile i.
// ---------------------------------------------------------------------------
__global__ __launch_bounds__(256, 2) void conv_main(
        const unsigned short* __restrict__ xT,
        const unsigned short* __restrict__ W2,
        const int*   __restrict__ nb,
        const float* __restrict__ bias,
        const float* __restrict__ inv_tv,
        const unsigned short* __restrict__ zbuf,
        float* __restrict__ out) {
    __shared__ __align__(16) unsigned short feat[2][7][HT2][64]; // 57,344 B

    int bid = blockIdx.x;
    int swz   = (bid & 7) * CPX2 + (bid >> 3);   // bijective XCD swizzle
    int gbase = swz * TPBLK;

    int t = threadIdx.x;
    int w = t >> 6;          // wave 0..3
    int l = t & 63;

    // staging lane constants
    int lrow = l >> 3;                  // h row within an 8-row chunk
    int jsrc = (l & 7) ^ lrow;          // source 16B unit (inverse of read swz)
    int slotA = w;                      // slot A for this wave
    int slotB = w + 4;                  // slot B (waves 0..2 only)
    bool hasB = (w < 3);
    int qA = slotA - 1;                 // -1 => center row
    int qB = slotB - 1;

    // compute lane constants
    int ogp = w & 1, hh = w >> 1;
    int lr = l & 15, lg = l >> 4;
    int hrow = hh * 16 + lr;            // 0..31

    // hoist W fragments + epilogue constants
    const bf16x8* __restrict__ Wf = reinterpret_cast<const bf16x8*>(W2);
    bf16x8 wr[NSTEP][2];
    #pragma unroll
    for (int s = 0; s < NSTEP; ++s)
        #pragma unroll
        for (int u = 0; u < 2; ++u)
            wr[s][u] = Wf[(s * 4 + ogp * 2 + u) * 64 + l];
    float inv = *inv_tv;
    float bv0[4], bv1[4];
    #pragma unroll
    for (int r = 0; r < 4; ++r) {
        bv0[r] = bias[ogp * 32 + lg * 4 + r];
        bv1[r] = bias[ogp * 32 + 16 + lg * 4 + r];
    }

    int nbvA[4], nbvB[4];    // neighbor rows for the tile staged next
    int bn, h0n;             // b / h0 of that tile

    // ---- prologue: stage tile 0, prefetch nbv for tile 1 -----------------
    {
        int b0  = gbase / TPB;
        int h00 = (gbase - b0 * TPB) * HT2;
        #pragma unroll
        for (int c = 0; c < 4; ++c) {
            int h = h00 + c * 8 + lrow;
            nbvA[c] = (h < H_) ? ((qA < 0) ? h : nb[h * 6 + qA]) : -1;
            nbvB[c] = (hasB && h < H_) ? nb[h * 6 + qB] : -1;
        }
        const unsigned short* xb = xT + (size_t)b0 * H_ * 64;
        #pragma unroll
        for (int c = 0; c < 4; ++c) {
            int n = nbvA[c];
            const unsigned short* src = (n >= 0)
                ? (xb + (size_t)n * 64 + jsrc * 8) : (zbuf + jsrc * 8);
            __builtin_amdgcn_global_load_lds((glb_u32*)src,
                (lds_u32*)&feat[0][slotA][c * 8][0], 16, 0, 0);
        }
        if (hasB) {
            #pragma unroll
            for (int c = 0; c < 4; ++c) {
                int n = nbvB[c];
                const unsigned short* src = (n >= 0)
                    ? (xb + (size_t)n * 64 + jsrc * 8) : (zbuf + jsrc * 8);
                __builtin_amdgcn_global_load_lds((glb_u32*)src,
                    (lds_u32*)&feat[0][slotB][c * 8][0], 16, 0, 0);
            }
        }
        int g1 = gbase + 1;
        bn  = g1 / TPB;
        h0n = (g1 - bn * TPB) * HT2;
        #pragma unroll
        for (int c = 0; c < 4; ++c) {
            int h = h0n + c * 8 + lrow;
            nbvA[c] = (h < H_) ? ((qA < 0) ? h : nb[h * 6 + qA]) : -1;
            nbvB[c] = (hasB && h < H_) ? nb[h * 6 + qB] : -1;
        }
    }

    // ---- main loop over 8 tiles -----------------------------------------
    #pragma unroll 2
    for (int i = 0; i < TPBLK; ++i) {
        // A: issue staging for tile i+1 into buf[(i+1)&1]
        if (i < TPBLK - 1) {
            const unsigned short* xb = xT + (size_t)bn * H_ * 64;
            int nbuf = (i + 1) & 1;
            #pragma unroll
            for (int c = 0; c < 4; ++c) {
                int n = nbvA[c];
                const unsigned short* src = (n >= 0)
                    ? (xb + (size_t)n * 64 + jsrc * 8) : (zbuf + jsrc * 8);
                __builtin_amdgcn_global_load_lds((glb_u32*)src,
                    (lds_u32*)&feat[nbuf][slotA][c * 8][0], 16, 0, 0);
            }
            if (hasB) {
                #pragma unroll
                for (int c = 0; c < 4; ++c) {
                    int n = nbvB[c];
                    const unsigned short* src = (n >= 0)
                        ? (xb + (size_t)n * 64 + jsrc * 8) : (zbuf + jsrc * 8);
                    __builtin_amdgcn_global_load_lds((glb_u32*)src,
                        (lds_u32*)&feat[nbuf][slotB][c * 8][0], 16, 0, 0);
                }
            }
        }
        // B: prefetch nbv for tile i+2
        if (i < TPBLK - 2) {
            int g2 = gbase + i + 2;
            bn  = g2 / TPB;
            h0n = (g2 - bn * TPB) * HT2;
            #pragma unroll
            for (int c = 0; c < 4; ++c) {
                int h = h0n + c * 8 + lrow;
                nbvA[c] = (h < H_) ? ((qA < 0) ? h : nb[h * 6 + qA]) : -1;
                nbvB[c] = (hasB && h < H_) ? nb[h * 6 + qB] : -1;
            }
        }
        // C: counted wait for tile-i staging. FIFO per wave:
        // [stage_i(G), nb_{i-1}(G), stores_{i-1}(8), A_i(G), B_i(G)], G=8 (w<3) / 4.
        // Allowing the 2G newest (A_i+B_i) to stay in flight => vmcnt(16)/(8);
        // final iterations fall back to vmcnt(8) (covers remaining stores).
        if (w < 3 && i < TPBLK - 1)
            asm volatile("s_waitcnt vmcnt(16)" ::: "memory");
        else
            asm volatile("s_waitcnt vmcnt(8)" ::: "memory");
        __builtin_amdgcn_s_barrier();
        __builtin_amdgcn_sched_barrier(0);

        // E: compute tile i from buf[i&1]; one bfrag feeds two MFMAs
        int cb = i & 1;
        f32x4 acc0 = (f32x4){0.f, 0.f, 0.f, 0.f};
        f32x4 acc1 = (f32x4){0.f, 0.f, 0.f, 0.f};
        #pragma unroll
        for (int s = 0; s < NSTEP; ++s) {
            int c16 = (((s & 1) * 4 + lg)) ^ (hrow & 7);
            bf16x8 bfrag = *reinterpret_cast<const bf16x8*>(
                    &feat[cb][s >> 1][hrow][c16 * 8]);
            acc0 = __builtin_amdgcn_mfma_f32_16x16x32_bf16(wr[s][0], bfrag, acc0, 0, 0, 0);
            acc1 = __builtin_amdgcn_mfma_f32_16x16x32_bf16(wr[s][1], bfrag, acc1, 0, 0, 0);
        }

        // F: epilogue for tile i (8 stores: 2 o-tiles x 4 rows)
        int g    = gbase + i;
        int curb = g / TPB;
        int curh = (g - curb * TPB) * HT2 + hrow;
        if (curh < H_) {
            float* ob = out + (size_t)curb * COUT * H_ + curh;
            #pragma unroll
            for (int r = 0; r < 4; ++r) {
                ob[(size_t)(ogp * 32 + lg * 4 + r) * H_]      = acc0[r] * inv + bv0[r];
                ob[(size_t)(ogp * 32 + 16 + lg * 4 + r) * H_] = acc1[r] * inv + bv1[r];
            }
        }

        // G: all reads of buf[i&1] done before next iter's staging overwrites
        __builtin_amdgcn_s_barrier();
    }
}

// ---------------------------------------------------------------------------
extern "C" void kernel_launch(void* const* d_in, const int* in_sizes, int n_in,
                              void* d_out, int out_size, void* d_ws, size_t ws_size,
                              hipStream_t stream) {
    const float* x    = (const float*)d_in[0];
    const int*   nb   = (const int*)  d_in[1];
    const float* wc   = (const float*)d_in[2];
    const float* wn   = (const float*)d_in[3];
    const float* bias = (const float*)d_in[4];
    float* out = (float*)d_out;

    char* ws = (char*)d_ws;
    unsigned short* W2     = (unsigned short*)ws;            // 57,344 B
    float*          inv_tv = (float*)(ws + 57344);           // 4 B
    unsigned short* zbuf   = (unsigned short*)(ws + 57472);  // 128 B zero
    unsigned short* xT     = (unsigned short*)(ws + 57600);  // 60,784,640 B

    prep_weights<<<112, 256, 0, stream>>>(wc, wn, nb, W2, inv_tv, zbuf);

    dim3 tgrid(NHT, B_);
    transpose_bf16<<<tgrid, 256, 0, stream>>>(x, xT);
    conv_main<<<NBLK, 256, 0, stream>>>(xT, W2, nb, bias, inv_tv, zbuf, out);
}